// Round 7
// baseline (270.777 us; speedup 1.0000x reference)
//
#include <hip/hip_runtime.h>

#define N_NODES 100000
#define N_EDGES 1600000
#define NBUCK 391   // dst buckets of 256 nodes (dst>>8)
#define CHUNKA 4096
#define NBLKA 391   // ceil(N_EDGES/CHUNKA); all chunk sizes divisible by 4

typedef __bf16 bf16x8 __attribute__((ext_vector_type(8)));
typedef float f32x4 __attribute__((ext_vector_type(4)));
typedef float f32x2 __attribute__((ext_vector_type(2)));

// fp32 -> bf16 (RNE) as ushort
__device__ inline unsigned short bf1(float a) {
    unsigned u = __builtin_bit_cast(unsigned, a);
    u = (u + 0x7FFF + ((u >> 16) & 1)) >> 16;
    return (unsigned short)u;
}
// pack two fp32 -> two bf16 in one uint (a=low, b=high)
__device__ inline unsigned bfpack(float a, float b) {
    unsigned ua = __builtin_bit_cast(unsigned, a);
    unsigned ub = __builtin_bit_cast(unsigned, b);
    ua = (ua + 0x7FFF + ((ua >> 16) & 1)) >> 16;
    ub = (ub + 0x7FFF + ((ub >> 16) & 1)) >> 16;
    return ua | (ub << 16);
}
__device__ inline float bflo(unsigned v) { return __builtin_bit_cast(float, v << 16); }
__device__ inline float bfhi(unsigned v) { return __builtin_bit_cast(float, v & 0xFFFF0000u); }

// ---------------- bucket histogram (LDS-privatized, int4 reads) + W transpose ----------------
// blocks 0..NBLKA-1: dst-bucket histogram; block NBLKA: Wt1; block NBLKA+1: Wt2.
__global__ __launch_bounds__(256) void bhist_kernel(const int* __restrict__ ei,
                                                    int* __restrict__ bhist,
                                                    const float* __restrict__ W1,
                                                    const float* __restrict__ W2,
                                                    unsigned short* __restrict__ Wt1,
                                                    unsigned short* __restrict__ Wt2) {
    const int t = threadIdx.x;
    if (blockIdx.x >= NBLKA) {
        if (blockIdx.x == NBLKA) {
            for (int i = t; i < 128 * 128; i += 256) {
                int k = i >> 7, n = i & 127;
                Wt1[n * 128 + k] = bf1(W1[i]);
            }
        } else {
            for (int i = t; i < 128 * 64; i += 256) {
                int k = i >> 6, n = i & 63;
                Wt2[n * 128 + k] = bf1(W2[i]);
            }
        }
        return;
    }
    __shared__ int hist[NBUCK];
    const int e0 = blockIdx.x * CHUNKA;
    const int n  = min(CHUNKA, N_EDGES - e0);   // always divisible by 4
    for (int i = t; i < NBUCK; i += 256) hist[i] = 0;
    __syncthreads();
    const int4* __restrict__ dst4 = (const int4*)(ei + N_EDGES + e0);
    const int n4 = n >> 2;
    for (int i = t; i < n4; i += 256) {
        int4 d = dst4[i];
        atomicAdd(&hist[d.x >> 8], 1);
        atomicAdd(&hist[d.y >> 8], 1);
        atomicAdd(&hist[d.z >> 8], 1);
        atomicAdd(&hist[d.w >> 8], 1);
    }
    __syncthreads();
    for (int i = t; i < NBUCK; i += 256)
        if (hist[i]) atomicAdd(&bhist[i], hist[i]);
}

// ---------------- prep: bucket exclusive scan ----------------
__global__ __launch_bounds__(512) void prep_kernel(const int* __restrict__ bhist,
                                                   int* __restrict__ boffs) {
    const int t = threadIdx.x;
    __shared__ int s[512];
    int v = (t < NBUCK) ? bhist[t] : 0;
    s[t] = v;
    __syncthreads();
#pragma unroll
    for (int off = 1; off < 512; off <<= 1) {
        int tv = (t >= off) ? s[t - off] : 0;
        __syncthreads();
        s[t] += tv;
        __syncthreads();
    }
    if (t < NBUCK) boffs[t] = s[t] - v;          // exclusive
    if (t == NBUCK - 1) boffs[NBUCK] = s[t];     // total = N_EDGES
}

// ---------------- CSR build pass A: scatter packed (src<<8)|(dst&255) per bucket ----------------
__global__ __launch_bounds__(256) void binA_kernel(const int* __restrict__ ei,
                                                   const int* __restrict__ boffs,
                                                   int* __restrict__ bcur,
                                                   unsigned* __restrict__ epk) {
    __shared__ int hist[NBUCK], base[NBUCK], cur[NBUCK];
    const int t = threadIdx.x;
    const int e0 = blockIdx.x * CHUNKA;
    const int n  = min(CHUNKA, N_EDGES - e0);   // divisible by 4
    const int n4 = n >> 2;
    const int4* __restrict__ src4 = (const int4*)(ei + e0);
    const int4* __restrict__ dst4 = (const int4*)(ei + N_EDGES + e0);
    for (int i = t; i < NBUCK; i += 256) hist[i] = 0;
    __syncthreads();
    for (int i = t; i < n4; i += 256) {
        int4 d = dst4[i];
        atomicAdd(&hist[d.x >> 8], 1);
        atomicAdd(&hist[d.y >> 8], 1);
        atomicAdd(&hist[d.z >> 8], 1);
        atomicAdd(&hist[d.w >> 8], 1);
    }
    __syncthreads();
    for (int i = t; i < NBUCK; i += 256) {
        int h = hist[i];
        base[i] = boffs[i] + (h ? atomicAdd(&bcur[i], h) : 0);
        cur[i]  = 0;
    }
    __syncthreads();
    for (int i = t; i < n4; i += 256) {
        int4 s = src4[i];
        int4 d = dst4[i];
#define PUT(ss, dd)                                               \
        do {                                                      \
            int b = (dd) >> 8;                                    \
            int r = atomicAdd(&cur[b], 1);                        \
            epk[base[b] + r] = ((unsigned)(ss) << 8) | (unsigned)((dd) & 255); \
        } while (0)
        PUT(s.x, d.x); PUT(s.y, d.y); PUT(s.z, d.z); PUT(s.w, d.w);
#undef PUT
    }
}

// ---------------- CSR build pass B: per-bucket deg/offs/dis + fine sort ----------------
__global__ __launch_bounds__(256) void binB_kernel(const unsigned* __restrict__ epk,
                                                   const int* __restrict__ boffs,
                                                   int* __restrict__ deg,
                                                   float* __restrict__ dis,
                                                   int* __restrict__ offs,
                                                   int* __restrict__ srcn) {
    __shared__ int cnt[256], s[256], loff[256];
    const int b  = blockIdx.x;
    const int t  = threadIdx.x;
    const int n0 = b << 8;
    const int base = boffs[b];
    const int end  = boffs[b + 1];
    cnt[t] = 0;
    __syncthreads();
    for (int e = base + t; e < end; e += 256)
        atomicAdd(&cnt[epk[e] & 255u], 1);
    __syncthreads();
    // exclusive scan of cnt
    int v = cnt[t];
    s[t] = v;
    __syncthreads();
#pragma unroll
    for (int off = 1; off < 256; off <<= 1) {
        int tv = (t >= off) ? s[t - off] : 0;
        __syncthreads();
        s[t] += tv;
        __syncthreads();
    }
    loff[t] = s[t] - v;
    {
        int node = n0 + t;
        if (node < N_NODES) {
            deg[node]  = v;
            dis[node]  = (v > 0) ? rsqrtf((float)v) : 0.0f;
            offs[node] = base + loff[t];
        }
    }
    cnt[t] = 0;   // reuse as cursor
    __syncthreads();
    for (int e = base + t; e < end; e += 256) {
        unsigned p = epk[e];
        int li  = (int)(p & 255u);
        int r   = atomicAdd(&cnt[li], 1);
        srcn[base + loff[li] + r] = (int)(p >> 8);
    }
}

// ---------------- GEMM1 (MFMA): h1b[N,128](bf16) = (x @ W1) * dis[n] ----------------
__global__ __launch_bounds__(256) void gemm1_kernel(const float* __restrict__ x,
                                                    const unsigned short* __restrict__ Wt1,
                                                    const float* __restrict__ dis,
                                                    unsigned short* __restrict__ h1b) {
    __shared__ unsigned short Asm[64][136];  // row stride 272B (16B-aligned), padded
    __shared__ float diss[64];
    const int t = threadIdx.x;
    const int node0 = blockIdx.x * 64;

#pragma unroll
    for (int c = 0; c < 4; ++c) {
        int i = c * 256 + t;            // 0..1023
        int row = i >> 4, ko = (i & 15) * 8;
        int gn = node0 + row;
        float4 v0 = make_float4(0, 0, 0, 0), v1 = v0;
        if (gn < N_NODES) {
            const float* p = x + (size_t)gn * 128 + ko;
            v0 = *(const float4*)p;
            v1 = *(const float4*)(p + 4);
        }
        uint4 o;
        o.x = bfpack(v0.x, v0.y); o.y = bfpack(v0.z, v0.w);
        o.z = bfpack(v1.x, v1.y); o.w = bfpack(v1.z, v1.w);
        *(uint4*)&Asm[row][ko] = o;
    }
    if (t < 64) {
        int gn = node0 + t;
        diss[t] = (gn < N_NODES) ? dis[gn] : 0.0f;
    }
    __syncthreads();

    const int wv = t >> 6, ln = t & 63;
    const int lc = ln & 15, q = ln >> 4;
    const int n0 = wv * 32;

    bf16x8 bfr[2][4];
#pragma unroll
    for (int nt = 0; nt < 2; ++nt)
#pragma unroll
        for (int k = 0; k < 4; ++k)
            bfr[nt][k] = *(const bf16x8*)(Wt1 + (size_t)(n0 + nt * 16 + lc) * 128 + k * 32 + q * 8);

    f32x4 acc[4][2];
#pragma unroll
    for (int m = 0; m < 4; ++m)
#pragma unroll
        for (int nt = 0; nt < 2; ++nt) acc[m][nt] = (f32x4)(0.0f);

#pragma unroll
    for (int k = 0; k < 4; ++k) {
        bf16x8 af[4];
#pragma unroll
        for (int m = 0; m < 4; ++m)
            af[m] = *(const bf16x8*)&Asm[m * 16 + lc][k * 32 + q * 8];
#pragma unroll
        for (int m = 0; m < 4; ++m)
#pragma unroll
            for (int nt = 0; nt < 2; ++nt)
                acc[m][nt] = __builtin_amdgcn_mfma_f32_16x16x32_bf16(af[m], bfr[nt][k], acc[m][nt], 0, 0, 0);
    }

    // C row = m*16 + q*4 + r, col = n0 + nt*16 + lc  [m89/m91 layout]
#pragma unroll
    for (int m = 0; m < 4; ++m)
#pragma unroll
        for (int r = 0; r < 4; ++r) {
            int lr = m * 16 + q * 4 + r;
            int gn = node0 + lr;
            if (gn < N_NODES) {
                float dv = diss[lr];
#pragma unroll
                for (int nt = 0; nt < 2; ++nt)
                    h1b[(size_t)gn * 128 + n0 + nt * 16 + lc] = bf1(acc[m][nt][r] * dv);
            }
        }
}

// ---------------- FUSED agg1 + GEMM2 ----------------
// Phase 1: quarter-wave edge-parallel gather (16 lanes x dwordx4 = one 256B
// h1b row per quarter-wave; 4 independent chains per wave), unrolled 8-deep,
// packed-f32 (v_pk_add_f32) accumulate. z = relu(dis*sum + b1) -> bf16 LDS.
// Phase 2: MFMA z @ W2t (verified form).
__global__ __launch_bounds__(256) void agg1gemm2_kernel(const int* __restrict__ srcn,
                                                        const int* __restrict__ offs,
                                                        const int* __restrict__ deg,
                                                        const float* __restrict__ dis,
                                                        const unsigned short* __restrict__ h1b,
                                                        const float* __restrict__ b1,
                                                        const unsigned short* __restrict__ Wt2,
                                                        unsigned short* __restrict__ h2b) {
    __shared__ unsigned short Zs[64][136];  // z rows, bf16, padded (272B stride)
    __shared__ float diss[64];
    __shared__ int offs_s[64], deg_s[64];
    const int t = threadIdx.x;
    const int node0 = blockIdx.x * 64;
    if (t < 64) {
        int gn = node0 + t;
        bool ok = gn < N_NODES;
        offs_s[t] = ok ? offs[gn] : 0;
        deg_s[t]  = ok ? deg[gn] : 0;
        diss[t]   = ok ? dis[gn] : 0.0f;
    }
    __syncthreads();

    const int wv = t >> 6, ln = t & 63;
    const int qw = ln >> 4, lc = ln & 15;   // quarter-wave id, lane-in-quarter
    const uint4* __restrict__ h1q = (const uint4*)h1b;  // row = 16 uint4

    float4 bbA = *(const float4*)(b1 + lc * 8);
    float4 bbB = *(const float4*)(b1 + lc * 8 + 4);

#define ACC8(v)                                           \
    do {                                                  \
        g0 += (f32x2){bflo((v).x), bfhi((v).x)};          \
        g1 += (f32x2){bflo((v).y), bfhi((v).y)};          \
        g2 += (f32x2){bflo((v).z), bfhi((v).z)};          \
        g3 += (f32x2){bflo((v).w), bfhi((v).w)};          \
    } while (0)

    for (int r = 0; r < 4; ++r) {
        const int lr  = wv * 16 + r * 4 + qw;
        const int beg = offs_s[lr];
        const int d   = deg_s[lr];
        f32x2 g0 = (f32x2)(0.0f), g1 = (f32x2)(0.0f),
              g2 = (f32x2)(0.0f), g3 = (f32x2)(0.0f);
        int k = 0;
        for (; k + 8 <= d; k += 8) {
            int s0 = srcn[beg + k];
            int s1 = srcn[beg + k + 1];
            int s2 = srcn[beg + k + 2];
            int s3 = srcn[beg + k + 3];
            int s4 = srcn[beg + k + 4];
            int s5 = srcn[beg + k + 5];
            int s6 = srcn[beg + k + 6];
            int s7 = srcn[beg + k + 7];
            uint4 v0 = h1q[(size_t)s0 * 16 + lc];
            uint4 v1 = h1q[(size_t)s1 * 16 + lc];
            uint4 v2 = h1q[(size_t)s2 * 16 + lc];
            uint4 v3 = h1q[(size_t)s3 * 16 + lc];
            uint4 v4 = h1q[(size_t)s4 * 16 + lc];
            uint4 v5 = h1q[(size_t)s5 * 16 + lc];
            uint4 v6 = h1q[(size_t)s6 * 16 + lc];
            uint4 v7 = h1q[(size_t)s7 * 16 + lc];
            ACC8(v0); ACC8(v1); ACC8(v2); ACC8(v3);
            ACC8(v4); ACC8(v5); ACC8(v6); ACC8(v7);
        }
        for (; k + 4 <= d; k += 4) {
            int s0 = srcn[beg + k];
            int s1 = srcn[beg + k + 1];
            int s2 = srcn[beg + k + 2];
            int s3 = srcn[beg + k + 3];
            uint4 v0 = h1q[(size_t)s0 * 16 + lc];
            uint4 v1 = h1q[(size_t)s1 * 16 + lc];
            uint4 v2 = h1q[(size_t)s2 * 16 + lc];
            uint4 v3 = h1q[(size_t)s3 * 16 + lc];
            ACC8(v0); ACC8(v1); ACC8(v2); ACC8(v3);
        }
        for (; k < d; ++k) {
            int s = srcn[beg + k];
            uint4 v = h1q[(size_t)s * 16 + lc];
            ACC8(v);
        }
        float dv = diss[lr];
        uint4 o;
        o.x = bfpack(fmaxf(dv * g0.x + bbA.x, 0.0f), fmaxf(dv * g0.y + bbA.y, 0.0f));
        o.y = bfpack(fmaxf(dv * g1.x + bbA.z, 0.0f), fmaxf(dv * g1.y + bbA.w, 0.0f));
        o.z = bfpack(fmaxf(dv * g2.x + bbB.x, 0.0f), fmaxf(dv * g2.y + bbB.y, 0.0f));
        o.w = bfpack(fmaxf(dv * g3.x + bbB.z, 0.0f), fmaxf(dv * g3.y + bbB.w, 0.0f));
        *(uint4*)&Zs[lr][lc * 8] = o;
    }
#undef ACC8
    __syncthreads();

    // Phase 2: MFMA (identical structure to verified gemm2)
    const int lc2 = ln & 15, q = ln >> 4;
    const int n0 = wv * 16;

    bf16x8 bfr[4];
#pragma unroll
    for (int k = 0; k < 4; ++k)
        bfr[k] = *(const bf16x8*)(Wt2 + (size_t)(n0 + lc2) * 128 + k * 32 + q * 8);

    f32x4 acc[4];
#pragma unroll
    for (int m = 0; m < 4; ++m) acc[m] = (f32x4)(0.0f);

#pragma unroll
    for (int k = 0; k < 4; ++k) {
        bf16x8 af[4];
#pragma unroll
        for (int m = 0; m < 4; ++m)
            af[m] = *(const bf16x8*)&Zs[m * 16 + lc2][k * 32 + q * 8];
#pragma unroll
        for (int m = 0; m < 4; ++m)
            acc[m] = __builtin_amdgcn_mfma_f32_16x16x32_bf16(af[m], bfr[k], acc[m], 0, 0, 0);
    }

#pragma unroll
    for (int m = 0; m < 4; ++m)
#pragma unroll
        for (int r = 0; r < 4; ++r) {
            int lr = m * 16 + q * 4 + r;
            int gn = node0 + lr;
            if (gn < N_NODES) {
                float dv = diss[lr];
                h2b[(size_t)gn * 64 + n0 + lc2] = bf1(acc[m][r] * dv);
            }
        }
}

// ---------------- agg2: quarter-wave edge-parallel, width 64 bf16, unroll 8, pk-add ----------------
__global__ __launch_bounds__(256) void agg2_kernel(const int* __restrict__ srcn,
                                                   const int* __restrict__ offs,
                                                   const int* __restrict__ deg,
                                                   const float* __restrict__ dis,
                                                   const unsigned short* __restrict__ h2b,
                                                   const float* __restrict__ b2,
                                                   float* __restrict__ out) {
    __shared__ float diss[64];
    __shared__ int offs_s[64], deg_s[64];
    const int t = threadIdx.x;
    const int node0 = blockIdx.x * 64;
    if (t < 64) {
        int gn = node0 + t;
        bool ok = gn < N_NODES;
        offs_s[t] = ok ? offs[gn] : 0;
        deg_s[t]  = ok ? deg[gn] : 0;
        diss[t]   = ok ? dis[gn] : 0.0f;
    }
    __syncthreads();

    const int wv = t >> 6, ln = t & 63;
    const int qw = ln >> 4, lc = ln & 15;
    const uint2* __restrict__ h2v = (const uint2*)h2b;  // row = 16 uint2

    float4 bb = *(const float4*)(b2 + lc * 4);

#define ACC4(v)                                           \
    do {                                                  \
        g0 += (f32x2){bflo((v).x), bfhi((v).x)};          \
        g1 += (f32x2){bflo((v).y), bfhi((v).y)};          \
    } while (0)

    for (int r = 0; r < 4; ++r) {
        const int lr  = wv * 16 + r * 4 + qw;
        const int beg = offs_s[lr];
        const int d   = deg_s[lr];
        f32x2 g0 = (f32x2)(0.0f), g1 = (f32x2)(0.0f);
        int k = 0;
        for (; k + 8 <= d; k += 8) {
            int s0 = srcn[beg + k];
            int s1 = srcn[beg + k + 1];
            int s2 = srcn[beg + k + 2];
            int s3 = srcn[beg + k + 3];
            int s4 = srcn[beg + k + 4];
            int s5 = srcn[beg + k + 5];
            int s6 = srcn[beg + k + 6];
            int s7 = srcn[beg + k + 7];
            uint2 v0 = h2v[(size_t)s0 * 16 + lc];
            uint2 v1 = h2v[(size_t)s1 * 16 + lc];
            uint2 v2 = h2v[(size_t)s2 * 16 + lc];
            uint2 v3 = h2v[(size_t)s3 * 16 + lc];
            uint2 v4 = h2v[(size_t)s4 * 16 + lc];
            uint2 v5 = h2v[(size_t)s5 * 16 + lc];
            uint2 v6 = h2v[(size_t)s6 * 16 + lc];
            uint2 v7 = h2v[(size_t)s7 * 16 + lc];
            ACC4(v0); ACC4(v1); ACC4(v2); ACC4(v3);
            ACC4(v4); ACC4(v5); ACC4(v6); ACC4(v7);
        }
        for (; k + 4 <= d; k += 4) {
            int s0 = srcn[beg + k];
            int s1 = srcn[beg + k + 1];
            int s2 = srcn[beg + k + 2];
            int s3 = srcn[beg + k + 3];
            uint2 v0 = h2v[(size_t)s0 * 16 + lc];
            uint2 v1 = h2v[(size_t)s1 * 16 + lc];
            uint2 v2 = h2v[(size_t)s2 * 16 + lc];
            uint2 v3 = h2v[(size_t)s3 * 16 + lc];
            ACC4(v0); ACC4(v1); ACC4(v2); ACC4(v3);
        }
        for (; k < d; ++k) {
            int s = srcn[beg + k];
            uint2 v = h2v[(size_t)s * 16 + lc];
            ACC4(v);
        }
        int gn = node0 + lr;
        if (gn < N_NODES) {
            float dv = diss[lr];
            float4 o;
            o.x = dv * g0.x + bb.x;
            o.y = dv * g0.y + bb.y;
            o.z = dv * g1.x + bb.z;
            o.w = dv * g1.y + bb.w;
            *(float4*)(out + (size_t)gn * 64 + lc * 4) = o;
        }
    }
#undef ACC4
}

extern "C" void kernel_launch(void* const* d_in, const int* in_sizes, int n_in,
                              void* d_out, int out_size, void* d_ws, size_t ws_size,
                              hipStream_t stream) {
    const float* x  = (const float*)d_in[0];
    const int*   ei = (const int*)d_in[1];
    const float* W1 = (const float*)d_in[2];
    const float* b1 = (const float*)d_in[3];
    const float* W2 = (const float*)d_in[4];
    const float* b2 = (const float*)d_in[5];
    float* out = (float*)d_out;

    char* ws = (char*)d_ws;
    int*   bhist = (int*)(ws);                           // 1.6 KB  @ 0
    int*   bcur  = (int*)(ws + (size_t)4 * 1024);        // 1.6 KB  @ 4 KB
    int*   boffs = (int*)(ws + (size_t)8 * 1024);        // 1.6 KB  @ 8 KB
    int*   deg   = (int*)(ws + (size_t)16 * 1024);       // 400 KB  @ 16 KB
    int*   offs  = (int*)(ws + (size_t)512 * 1024);      // 400 KB  @ 512 KB
    float* dis   = (float*)(ws + (size_t)1024 * 1024);   // 400 KB  @ 1 MB
    unsigned short* Wt1 = (unsigned short*)(ws + (size_t)1536 * 1024);  // 32 KB @ 1.5 MB
    unsigned short* Wt2 = (unsigned short*)(ws + (size_t)1600 * 1024);  // 16 KB
    unsigned* epk = (unsigned*)(ws + (size_t)2560 * 1024);   // 6.4 MB @ 2.5 MB
    int*   srcn  = (int*)(ws + (size_t)9216 * 1024);     // 6.4 MB  @ 9 MB
    unsigned short* h1b = (unsigned short*)(ws + (size_t)16 * 1024 * 1024);  // 25.6 MB @ 16 MB
    unsigned short* h2b = (unsigned short*)(ws + (size_t)48 * 1024 * 1024); // 12.8 MB @ 48 MB

    hipMemsetAsync(ws, 0, (size_t)8 * 1024, stream);  // bhist + bcur

    bhist_kernel<<<NBLKA + 2, 256, 0, stream>>>(ei, bhist, W1, W2, Wt1, Wt2);
    prep_kernel<<<1, 512, 0, stream>>>(bhist, boffs);
    binA_kernel<<<NBLKA, 256, 0, stream>>>(ei, boffs, bcur, epk);
    binB_kernel<<<NBUCK, 256, 0, stream>>>(epk, boffs, deg, dis, offs, srcn);
    gemm1_kernel<<<(N_NODES + 63) / 64, 256, 0, stream>>>(x, Wt1, dis, h1b);
    agg1gemm2_kernel<<<(N_NODES + 63) / 64, 256, 0, stream>>>(srcn, offs, deg, dis,
                                                              h1b, b1, Wt2, h2b);
    agg2_kernel<<<(N_NODES + 63) / 64, 256, 0, stream>>>(srcn, offs, deg, dis,
                                                         h2b, b2, out);
}

// Round 8
// 257.093 us; speedup vs baseline: 1.0532x; 1.0532x over previous
//
#include <hip/hip_runtime.h>

#define N_NODES 100000
#define N_EDGES 1600000
#define NBUCK 391    // dst buckets of 256 nodes (dst>>8)
#define CHUNKA 4096
#define NBLKA 391    // ceil(N_EDGES/CHUNKA); all chunk sizes divisible by 4
#define ESTRIDE 6144 // fixed epk region per bucket (mean 4096, sigma~64 -> 32 sigma headroom)

typedef __bf16 bf16x8 __attribute__((ext_vector_type(8)));
typedef float f32x4 __attribute__((ext_vector_type(4)));
typedef float f32x2 __attribute__((ext_vector_type(2)));

// fp32 -> bf16 (RNE) as ushort
__device__ inline unsigned short bf1(float a) {
    unsigned u = __builtin_bit_cast(unsigned, a);
    u = (u + 0x7FFF + ((u >> 16) & 1)) >> 16;
    return (unsigned short)u;
}
// pack two fp32 -> two bf16 in one uint (a=low, b=high)
__device__ inline unsigned bfpack(float a, float b) {
    unsigned ua = __builtin_bit_cast(unsigned, a);
    unsigned ub = __builtin_bit_cast(unsigned, b);
    ua = (ua + 0x7FFF + ((ua >> 16) & 1)) >> 16;
    ub = (ub + 0x7FFF + ((ub >> 16) & 1)) >> 16;
    return ua | (ub << 16);
}
__device__ inline float bflo(unsigned v) { return __builtin_bit_cast(float, v << 16); }
__device__ inline float bfhi(unsigned v) { return __builtin_bit_cast(float, v & 0xFFFF0000u); }

// ---------------- single-pass CSR pass A: dynamic-claim scatter into fixed-stride buckets ----------------
// blocks 0..NBLKA-1: edge scatter; block NBLKA: Wt1 transpose; block NBLKA+1: Wt2 transpose.
__global__ __launch_bounds__(256) void binA_kernel(const int* __restrict__ ei,
                                                   int* __restrict__ bcur,
                                                   unsigned* __restrict__ epk,
                                                   const float* __restrict__ W1,
                                                   const float* __restrict__ W2,
                                                   unsigned short* __restrict__ Wt1,
                                                   unsigned short* __restrict__ Wt2) {
    const int t = threadIdx.x;
    if (blockIdx.x >= NBLKA) {
        if (blockIdx.x == NBLKA) {
            for (int i = t; i < 128 * 128; i += 256) {
                int k = i >> 7, n = i & 127;
                Wt1[n * 128 + k] = bf1(W1[i]);
            }
        } else {
            for (int i = t; i < 128 * 64; i += 256) {
                int k = i >> 6, n = i & 63;
                Wt2[n * 128 + k] = bf1(W2[i]);
            }
        }
        return;
    }
    __shared__ int hist[NBUCK], base[NBUCK], cur[NBUCK];
    const int e0 = blockIdx.x * CHUNKA;
    const int n  = min(CHUNKA, N_EDGES - e0);   // divisible by 4
    const int n4 = n >> 2;
    const int4* __restrict__ src4 = (const int4*)(ei + e0);
    const int4* __restrict__ dst4 = (const int4*)(ei + N_EDGES + e0);
    for (int i = t; i < NBUCK; i += 256) hist[i] = 0;
    __syncthreads();
    for (int i = t; i < n4; i += 256) {
        int4 d = dst4[i];
        atomicAdd(&hist[d.x >> 8], 1);
        atomicAdd(&hist[d.y >> 8], 1);
        atomicAdd(&hist[d.z >> 8], 1);
        atomicAdd(&hist[d.w >> 8], 1);
    }
    __syncthreads();
    for (int i = t; i < NBUCK; i += 256) {
        int h = hist[i];
        base[i] = i * ESTRIDE + (h ? atomicAdd(&bcur[i], h) : 0);
        cur[i]  = 0;
    }
    __syncthreads();
    for (int i = t; i < n4; i += 256) {
        int4 s = src4[i];
        int4 d = dst4[i];
#define PUT(ss, dd)                                               \
        do {                                                      \
            int b = (dd) >> 8;                                    \
            int r = atomicAdd(&cur[b], 1);                        \
            epk[base[b] + r] = ((unsigned)(ss) << 8) | (unsigned)((dd) & 255); \
        } while (0)
        PUT(s.x, d.x); PUT(s.y, d.y); PUT(s.z, d.z); PUT(s.w, d.w);
#undef PUT
    }
}

// ---------------- prep: exclusive scan of bucket totals -> boffs ----------------
__global__ __launch_bounds__(512) void prep_kernel(const int* __restrict__ bcur,
                                                   int* __restrict__ boffs) {
    const int t = threadIdx.x;
    __shared__ int s[512];
    int v = (t < NBUCK) ? bcur[t] : 0;
    s[t] = v;
    __syncthreads();
#pragma unroll
    for (int off = 1; off < 512; off <<= 1) {
        int tv = (t >= off) ? s[t - off] : 0;
        __syncthreads();
        s[t] += tv;
        __syncthreads();
    }
    if (t < NBUCK) boffs[t] = s[t] - v;          // exclusive
    if (t == NBUCK - 1) boffs[NBUCK] = s[t];     // total = N_EDGES
}

// ---------------- CSR pass B: per-bucket deg/offs/dis + fine sort ----------------
__global__ __launch_bounds__(256) void binB_kernel(const unsigned* __restrict__ epk,
                                                   const int* __restrict__ bcur,
                                                   const int* __restrict__ boffs,
                                                   int* __restrict__ deg,
                                                   float* __restrict__ dis,
                                                   int* __restrict__ offs,
                                                   int* __restrict__ srcn) {
    __shared__ int cnt[256], s[256], loff[256];
    const int b  = blockIdx.x;
    const int t  = threadIdx.x;
    const int n0 = b << 8;
    const int base  = b * ESTRIDE;
    const int end   = base + bcur[b];
    const int sbase = boffs[b];
    cnt[t] = 0;
    __syncthreads();
    for (int e = base + t; e < end; e += 256)
        atomicAdd(&cnt[epk[e] & 255u], 1);
    __syncthreads();
    // exclusive scan of cnt
    int v = cnt[t];
    s[t] = v;
    __syncthreads();
#pragma unroll
    for (int off = 1; off < 256; off <<= 1) {
        int tv = (t >= off) ? s[t - off] : 0;
        __syncthreads();
        s[t] += tv;
        __syncthreads();
    }
    loff[t] = s[t] - v;
    {
        int node = n0 + t;
        if (node < N_NODES) {
            deg[node]  = v;
            dis[node]  = (v > 0) ? rsqrtf((float)v) : 0.0f;
            offs[node] = sbase + loff[t];
        }
    }
    cnt[t] = 0;   // reuse as cursor
    __syncthreads();
    for (int e = base + t; e < end; e += 256) {
        unsigned p = epk[e];
        int li  = (int)(p & 255u);
        int r   = atomicAdd(&cnt[li], 1);
        srcn[sbase + loff[li] + r] = (int)(p >> 8);
    }
}

// ---------------- GEMM1 (MFMA): h1b[N,128](bf16) = (x @ W1) * dis[n] ----------------
__global__ __launch_bounds__(256) void gemm1_kernel(const float* __restrict__ x,
                                                    const unsigned short* __restrict__ Wt1,
                                                    const float* __restrict__ dis,
                                                    unsigned short* __restrict__ h1b) {
    __shared__ unsigned short Asm[64][136];  // row stride 272B (16B-aligned), padded
    __shared__ float diss[64];
    const int t = threadIdx.x;
    const int node0 = blockIdx.x * 64;

#pragma unroll
    for (int c = 0; c < 4; ++c) {
        int i = c * 256 + t;            // 0..1023
        int row = i >> 4, ko = (i & 15) * 8;
        int gn = node0 + row;
        float4 v0 = make_float4(0, 0, 0, 0), v1 = v0;
        if (gn < N_NODES) {
            const float* p = x + (size_t)gn * 128 + ko;
            v0 = *(const float4*)p;
            v1 = *(const float4*)(p + 4);
        }
        uint4 o;
        o.x = bfpack(v0.x, v0.y); o.y = bfpack(v0.z, v0.w);
        o.z = bfpack(v1.x, v1.y); o.w = bfpack(v1.z, v1.w);
        *(uint4*)&Asm[row][ko] = o;
    }
    if (t < 64) {
        int gn = node0 + t;
        diss[t] = (gn < N_NODES) ? dis[gn] : 0.0f;
    }
    __syncthreads();

    const int wv = t >> 6, ln = t & 63;
    const int lc = ln & 15, q = ln >> 4;
    const int n0 = wv * 32;

    bf16x8 bfr[2][4];
#pragma unroll
    for (int nt = 0; nt < 2; ++nt)
#pragma unroll
        for (int k = 0; k < 4; ++k)
            bfr[nt][k] = *(const bf16x8*)(Wt1 + (size_t)(n0 + nt * 16 + lc) * 128 + k * 32 + q * 8);

    f32x4 acc[4][2];
#pragma unroll
    for (int m = 0; m < 4; ++m)
#pragma unroll
        for (int nt = 0; nt < 2; ++nt) acc[m][nt] = (f32x4)(0.0f);

#pragma unroll
    for (int k = 0; k < 4; ++k) {
        bf16x8 af[4];
#pragma unroll
        for (int m = 0; m < 4; ++m)
            af[m] = *(const bf16x8*)&Asm[m * 16 + lc][k * 32 + q * 8];
#pragma unroll
        for (int m = 0; m < 4; ++m)
#pragma unroll
            for (int nt = 0; nt < 2; ++nt)
                acc[m][nt] = __builtin_amdgcn_mfma_f32_16x16x32_bf16(af[m], bfr[nt][k], acc[m][nt], 0, 0, 0);
    }

    // C row = m*16 + q*4 + r, col = n0 + nt*16 + lc  [m89/m91 layout]
#pragma unroll
    for (int m = 0; m < 4; ++m)
#pragma unroll
        for (int r = 0; r < 4; ++r) {
            int lr = m * 16 + q * 4 + r;
            int gn = node0 + lr;
            if (gn < N_NODES) {
                float dv = diss[lr];
#pragma unroll
                for (int nt = 0; nt < 2; ++nt)
                    h1b[(size_t)gn * 128 + n0 + nt * 16 + lc] = bf1(acc[m][nt][r] * dv);
            }
        }
}

// ---------------- FUSED agg1 + GEMM2 ----------------
// Phase 1: quarter-wave edge-parallel gather (16 lanes x dwordx4 = one 256B
// h1b row per quarter-wave; 4 independent chains per wave), unrolled 8-deep,
// packed-f32 accumulate. z = relu(dis*sum + b1) -> bf16 LDS.
// Phase 2: MFMA z @ W2t (verified form).
__global__ __launch_bounds__(256) void agg1gemm2_kernel(const int* __restrict__ srcn,
                                                        const int* __restrict__ offs,
                                                        const int* __restrict__ deg,
                                                        const float* __restrict__ dis,
                                                        const unsigned short* __restrict__ h1b,
                                                        const float* __restrict__ b1,
                                                        const unsigned short* __restrict__ Wt2,
                                                        unsigned short* __restrict__ h2b) {
    __shared__ unsigned short Zs[64][136];  // z rows, bf16, padded (272B stride)
    __shared__ float diss[64];
    __shared__ int offs_s[64], deg_s[64];
    const int t = threadIdx.x;
    const int node0 = blockIdx.x * 64;
    if (t < 64) {
        int gn = node0 + t;
        bool ok = gn < N_NODES;
        offs_s[t] = ok ? offs[gn] : 0;
        deg_s[t]  = ok ? deg[gn] : 0;
        diss[t]   = ok ? dis[gn] : 0.0f;
    }
    __syncthreads();

    const int wv = t >> 6, ln = t & 63;
    const int qw = ln >> 4, lc = ln & 15;   // quarter-wave id, lane-in-quarter
    const uint4* __restrict__ h1q = (const uint4*)h1b;  // row = 16 uint4

    float4 bbA = *(const float4*)(b1 + lc * 8);
    float4 bbB = *(const float4*)(b1 + lc * 8 + 4);

#define ACC8(v)                                           \
    do {                                                  \
        g0 += (f32x2){bflo((v).x), bfhi((v).x)};          \
        g1 += (f32x2){bflo((v).y), bfhi((v).y)};          \
        g2 += (f32x2){bflo((v).z), bfhi((v).z)};          \
        g3 += (f32x2){bflo((v).w), bfhi((v).w)};          \
    } while (0)

    for (int r = 0; r < 4; ++r) {
        const int lr  = wv * 16 + r * 4 + qw;
        const int beg = offs_s[lr];
        const int d   = deg_s[lr];
        f32x2 g0 = (f32x2)(0.0f), g1 = (f32x2)(0.0f),
              g2 = (f32x2)(0.0f), g3 = (f32x2)(0.0f);
        int k = 0;
        for (; k + 8 <= d; k += 8) {
            int s0 = srcn[beg + k];
            int s1 = srcn[beg + k + 1];
            int s2 = srcn[beg + k + 2];
            int s3 = srcn[beg + k + 3];
            int s4 = srcn[beg + k + 4];
            int s5 = srcn[beg + k + 5];
            int s6 = srcn[beg + k + 6];
            int s7 = srcn[beg + k + 7];
            uint4 v0 = h1q[(size_t)s0 * 16 + lc];
            uint4 v1 = h1q[(size_t)s1 * 16 + lc];
            uint4 v2 = h1q[(size_t)s2 * 16 + lc];
            uint4 v3 = h1q[(size_t)s3 * 16 + lc];
            uint4 v4 = h1q[(size_t)s4 * 16 + lc];
            uint4 v5 = h1q[(size_t)s5 * 16 + lc];
            uint4 v6 = h1q[(size_t)s6 * 16 + lc];
            uint4 v7 = h1q[(size_t)s7 * 16 + lc];
            ACC8(v0); ACC8(v1); ACC8(v2); ACC8(v3);
            ACC8(v4); ACC8(v5); ACC8(v6); ACC8(v7);
        }
        for (; k + 4 <= d; k += 4) {
            int s0 = srcn[beg + k];
            int s1 = srcn[beg + k + 1];
            int s2 = srcn[beg + k + 2];
            int s3 = srcn[beg + k + 3];
            uint4 v0 = h1q[(size_t)s0 * 16 + lc];
            uint4 v1 = h1q[(size_t)s1 * 16 + lc];
            uint4 v2 = h1q[(size_t)s2 * 16 + lc];
            uint4 v3 = h1q[(size_t)s3 * 16 + lc];
            ACC8(v0); ACC8(v1); ACC8(v2); ACC8(v3);
        }
        for (; k < d; ++k) {
            int s = srcn[beg + k];
            uint4 v = h1q[(size_t)s * 16 + lc];
            ACC8(v);
        }
        float dv = diss[lr];
        uint4 o;
        o.x = bfpack(fmaxf(dv * g0.x + bbA.x, 0.0f), fmaxf(dv * g0.y + bbA.y, 0.0f));
        o.y = bfpack(fmaxf(dv * g1.x + bbA.z, 0.0f), fmaxf(dv * g1.y + bbA.w, 0.0f));
        o.z = bfpack(fmaxf(dv * g2.x + bbB.x, 0.0f), fmaxf(dv * g2.y + bbB.y, 0.0f));
        o.w = bfpack(fmaxf(dv * g3.x + bbB.z, 0.0f), fmaxf(dv * g3.y + bbB.w, 0.0f));
        *(uint4*)&Zs[lr][lc * 8] = o;
    }
#undef ACC8
    __syncthreads();

    // Phase 2: MFMA (identical structure to verified gemm2)
    const int lc2 = ln & 15, q = ln >> 4;
    const int n0 = wv * 16;

    bf16x8 bfr[4];
#pragma unroll
    for (int k = 0; k < 4; ++k)
        bfr[k] = *(const bf16x8*)(Wt2 + (size_t)(n0 + lc2) * 128 + k * 32 + q * 8);

    f32x4 acc[4];
#pragma unroll
    for (int m = 0; m < 4; ++m) acc[m] = (f32x4)(0.0f);

#pragma unroll
    for (int k = 0; k < 4; ++k) {
        bf16x8 af[4];
#pragma unroll
        for (int m = 0; m < 4; ++m)
            af[m] = *(const bf16x8*)&Zs[m * 16 + lc2][k * 32 + q * 8];
#pragma unroll
        for (int m = 0; m < 4; ++m)
            acc[m] = __builtin_amdgcn_mfma_f32_16x16x32_bf16(af[m], bfr[k], acc[m], 0, 0, 0);
    }

#pragma unroll
    for (int m = 0; m < 4; ++m)
#pragma unroll
        for (int r = 0; r < 4; ++r) {
            int lr = m * 16 + q * 4 + r;
            int gn = node0 + lr;
            if (gn < N_NODES) {
                float dv = diss[lr];
                h2b[(size_t)gn * 64 + n0 + lc2] = bf1(acc[m][r] * dv);
            }
        }
}

// ---------------- agg2: quarter-wave edge-parallel, width 64 bf16, unroll 8, pk-add ----------------
__global__ __launch_bounds__(256) void agg2_kernel(const int* __restrict__ srcn,
                                                   const int* __restrict__ offs,
                                                   const int* __restrict__ deg,
                                                   const float* __restrict__ dis,
                                                   const unsigned short* __restrict__ h2b,
                                                   const float* __restrict__ b2,
                                                   float* __restrict__ out) {
    __shared__ float diss[64];
    __shared__ int offs_s[64], deg_s[64];
    const int t = threadIdx.x;
    const int node0 = blockIdx.x * 64;
    if (t < 64) {
        int gn = node0 + t;
        bool ok = gn < N_NODES;
        offs_s[t] = ok ? offs[gn] : 0;
        deg_s[t]  = ok ? deg[gn] : 0;
        diss[t]   = ok ? dis[gn] : 0.0f;
    }
    __syncthreads();

    const int wv = t >> 6, ln = t & 63;
    const int qw = ln >> 4, lc = ln & 15;
    const uint2* __restrict__ h2v = (const uint2*)h2b;  // row = 16 uint2

    float4 bb = *(const float4*)(b2 + lc * 4);

#define ACC4(v)                                           \
    do {                                                  \
        g0 += (f32x2){bflo((v).x), bfhi((v).x)};          \
        g1 += (f32x2){bflo((v).y), bfhi((v).y)};          \
    } while (0)

    for (int r = 0; r < 4; ++r) {
        const int lr  = wv * 16 + r * 4 + qw;
        const int beg = offs_s[lr];
        const int d   = deg_s[lr];
        f32x2 g0 = (f32x2)(0.0f), g1 = (f32x2)(0.0f);
        int k = 0;
        for (; k + 8 <= d; k += 8) {
            int s0 = srcn[beg + k];
            int s1 = srcn[beg + k + 1];
            int s2 = srcn[beg + k + 2];
            int s3 = srcn[beg + k + 3];
            int s4 = srcn[beg + k + 4];
            int s5 = srcn[beg + k + 5];
            int s6 = srcn[beg + k + 6];
            int s7 = srcn[beg + k + 7];
            uint2 v0 = h2v[(size_t)s0 * 16 + lc];
            uint2 v1 = h2v[(size_t)s1 * 16 + lc];
            uint2 v2 = h2v[(size_t)s2 * 16 + lc];
            uint2 v3 = h2v[(size_t)s3 * 16 + lc];
            uint2 v4 = h2v[(size_t)s4 * 16 + lc];
            uint2 v5 = h2v[(size_t)s5 * 16 + lc];
            uint2 v6 = h2v[(size_t)s6 * 16 + lc];
            uint2 v7 = h2v[(size_t)s7 * 16 + lc];
            ACC4(v0); ACC4(v1); ACC4(v2); ACC4(v3);
            ACC4(v4); ACC4(v5); ACC4(v6); ACC4(v7);
        }
        for (; k + 4 <= d; k += 4) {
            int s0 = srcn[beg + k];
            int s1 = srcn[beg + k + 1];
            int s2 = srcn[beg + k + 2];
            int s3 = srcn[beg + k + 3];
            uint2 v0 = h2v[(size_t)s0 * 16 + lc];
            uint2 v1 = h2v[(size_t)s1 * 16 + lc];
            uint2 v2 = h2v[(size_t)s2 * 16 + lc];
            uint2 v3 = h2v[(size_t)s3 * 16 + lc];
            ACC4(v0); ACC4(v1); ACC4(v2); ACC4(v3);
        }
        for (; k < d; ++k) {
            int s = srcn[beg + k];
            uint2 v = h2v[(size_t)s * 16 + lc];
            ACC4(v);
        }
        int gn = node0 + lr;
        if (gn < N_NODES) {
            float dv = diss[lr];
            float4 o;
            o.x = dv * g0.x + bb.x;
            o.y = dv * g0.y + bb.y;
            o.z = dv * g1.x + bb.z;
            o.w = dv * g1.y + bb.w;
            *(float4*)(out + (size_t)gn * 64 + lc * 4) = o;
        }
    }
#undef ACC4
}

extern "C" void kernel_launch(void* const* d_in, const int* in_sizes, int n_in,
                              void* d_out, int out_size, void* d_ws, size_t ws_size,
                              hipStream_t stream) {
    const float* x  = (const float*)d_in[0];
    const int*   ei = (const int*)d_in[1];
    const float* W1 = (const float*)d_in[2];
    const float* b1 = (const float*)d_in[3];
    const float* W2 = (const float*)d_in[4];
    const float* b2 = (const float*)d_in[5];
    float* out = (float*)d_out;

    char* ws = (char*)d_ws;
    int*   bcur  = (int*)(ws);                           // 1.6 KB  @ 0
    int*   boffs = (int*)(ws + (size_t)4 * 1024);        // 1.6 KB  @ 4 KB
    int*   deg   = (int*)(ws + (size_t)16 * 1024);       // 400 KB  @ 16 KB
    int*   offs  = (int*)(ws + (size_t)512 * 1024);      // 400 KB  @ 512 KB
    float* dis   = (float*)(ws + (size_t)1024 * 1024);   // 400 KB  @ 1 MB
    unsigned short* Wt1 = (unsigned short*)(ws + (size_t)1536 * 1024);  // 32 KB @ 1.5 MB
    unsigned short* Wt2 = (unsigned short*)(ws + (size_t)1600 * 1024);  // 16 KB
    unsigned* epk = (unsigned*)(ws + (size_t)2560 * 1024);   // 9.6 MB @ 2.5 MB (391*6144*4)
    int*   srcn  = (int*)(ws + (size_t)12800 * 1024);    // 6.4 MB  @ 12.5 MB
    unsigned short* h1b = (unsigned short*)(ws + (size_t)20 * 1024 * 1024);  // 25.6 MB @ 20 MB
    unsigned short* h2b = (unsigned short*)(ws + (size_t)46 * 1024 * 1024); // 12.8 MB @ 46 MB

    hipMemsetAsync(ws, 0, (size_t)2 * 1024, stream);  // bcur

    binA_kernel<<<NBLKA + 2, 256, 0, stream>>>(ei, bcur, epk, W1, W2, Wt1, Wt2);
    prep_kernel<<<1, 512, 0, stream>>>(bcur, boffs);
    binB_kernel<<<NBUCK, 256, 0, stream>>>(epk, bcur, boffs, deg, dis, offs, srcn);
    gemm1_kernel<<<(N_NODES + 63) / 64, 256, 0, stream>>>(x, Wt1, dis, h1b);
    agg1gemm2_kernel<<<(N_NODES + 63) / 64, 256, 0, stream>>>(srcn, offs, deg, dis,
                                                              h1b, b1, Wt2, h2b);
    agg2_kernel<<<(N_NODES + 63) / 64, 256, 0, stream>>>(srcn, offs, deg, dis,
                                                         h2b, b2, out);
}